// Round 18
// baseline (256.220 us; speedup 1.0000x reference)
//
#include <hip/hip_runtime.h>
#include <stdint.h>

#define DEV __device__ __forceinline__

typedef __bf16 bf16x8 __attribute__((ext_vector_type(8)));
typedef float f32x4 __attribute__((ext_vector_type(4)));
typedef float f32x16 __attribute__((ext_vector_type(16)));

DEV unsigned short f2bf(float f) {
  union { float f; uint32_t u; } c; c.f = f;
  uint32_t u = c.u;
  u += 0x7FFFu + ((u >> 16) & 1u);   // round-to-nearest-even
  return (unsigned short)(u >> 16);
}
DEV float bf2f(unsigned short h) {
  union { uint32_t u; float f; } c; c.u = ((uint32_t)h) << 16;
  return c.f;
}
DEV float u2f(uint32_t u) {
  union { uint32_t u; float f; } c; c.u = u;
  return c.f;
}
DEV bf16x8 ld8(const unsigned short* p) {
  uint4 u = *reinterpret_cast<const uint4*>(p);
  return __builtin_bit_cast(bf16x8, u);
}
DEV uint32_t cvtpk(float lo, float hi) {
  uint32_t r;
  asm("v_cvt_pk_bf16_f32 %0, %1, %2" : "=v"(r) : "v"(lo), "v"(hi));
  return r;
}
// NEW a[32:63] = OLD b[0:31]; NEW b[0:31] = OLD a[32:63]; rest unchanged.
DEV void permswap(uint32_t& a, uint32_t& b) {
  asm("v_permlane32_swap_b32 %0, %1" : "+v"(a), "+v"(b));
}
// exp2 via compiler builtin -> v_exp_f32 with trans-hazard handling
DEV float exp2b(float x) { return __builtin_amdgcn_exp2f(x); }
// async global->LDS, 16B per lane; LDS dest must be wave-uniform-base + lane*16
DEV void gload16(const void* g, void* l) {
  __builtin_amdgcn_global_load_lds((const __attribute__((address_space(1))) void*)g,
                                   (__attribute__((address_space(3))) void*)l, 16, 0, 0);
}

// ---------------------------------------------------------------------------
// Kernel 1: merged weight transpose+cast: w_qkv [1024][3072] and w_o
// [1024][1024] -> bf16 [N][K] in one launch (saves a dispatch).
// ---------------------------------------------------------------------------
__global__ __launch_bounds__(256)
void transpose_both_kernel(const float* __restrict__ wqkv, const float* __restrict__ wo,
                           unsigned short* __restrict__ oqkv, unsigned short* __restrict__ oo) {
  int bid = blockIdx.x;
  const float* in;
  unsigned short* out;
  int N;
  if (bid < 768) {                 // 16 k-blocks x 48 n-blocks
    in = wqkv; out = oqkv; N = 3072;
  } else {
    bid -= 768; in = wo; out = oo; N = 1024;   // 16 x 16
  }
  const int bk = bid & 15, bn = bid >> 4;
  const int k0 = bk * 64, n0 = bn * 64;
  const int t = threadIdx.x;
  __shared__ float tile[64][65];
#pragma unroll
  for (int i = 0; i < 16; ++i) {
    int idx = t + i * 256;
    int kl = idx >> 6, nl = idx & 63;
    tile[kl][nl] = in[(size_t)(k0 + kl) * N + n0 + nl];
  }
  __syncthreads();
#pragma unroll
  for (int i = 0; i < 16; ++i) {
    int idx = t + i * 256;
    int nl = idx >> 6, kl = idx & 63;
    out[(size_t)(n0 + nl) * 1024 + k0 + kl] = f2bf(tile[kl][nl]);
  }
}

// ---------------------------------------------------------------------------
// Kernel 2: LayerNorm (no beta) f32 -> bf16, one block per row of 1024
// ---------------------------------------------------------------------------
__global__ __launch_bounds__(256)
void ln_kernel(const float* __restrict__ x, const float* __restrict__ gamma,
               unsigned short* __restrict__ y) {
  const int row = blockIdx.x;
  const int t = threadIdx.x;
  const float4 v = reinterpret_cast<const float4*>(x + (size_t)row * 1024)[t];
  float s  = v.x + v.y + v.z + v.w;
  float s2 = v.x * v.x + v.y * v.y + v.z * v.z + v.w * v.w;
#pragma unroll
  for (int off = 1; off < 64; off <<= 1) {
    s  += __shfl_xor(s, off);
    s2 += __shfl_xor(s2, off);
  }
  __shared__ float red[8];
  const int w = t >> 6, lane = t & 63;
  if (lane == 0) { red[w] = s; red[4 + w] = s2; }
  __syncthreads();
  s  = red[0] + red[1] + red[2] + red[3];
  s2 = red[4] + red[5] + red[6] + red[7];
  const float mu = s * (1.0f / 1024.0f);
  const float var = s2 * (1.0f / 1024.0f) - mu * mu;
  const float rstd = rsqrtf(var + 1e-5f);
  const float4 g = reinterpret_cast<const float4*>(gamma)[t];
  ushort4 o;
  o.x = f2bf((v.x - mu) * rstd * g.x);
  o.y = f2bf((v.y - mu) * rstd * g.y);
  o.z = f2bf((v.z - mu) * rstd * g.z);
  o.w = f2bf((v.w - mu) * rstd * g.w);
  reinterpret_cast<ushort4*>(y + (size_t)row * 1024)[t] = o;
}

// ---------------------------------------------------------------------------
// Kernel 3: bf16 GEMM, A[M][1024] x Bt[N][1024]^T -> C[M][N] (f32 out).
// 128x128 tile, BK=32, 4 waves, 16x16x32 MFMA, global_load_lds staging.
// XCD-bijective block remap (T1). Used for the output projection.
// ---------------------------------------------------------------------------
template<int N_DIM>
__global__ __launch_bounds__(256)
void gemm_bt_kernel(const unsigned short* __restrict__ A,
                    const unsigned short* __restrict__ Bt,
                    float* __restrict__ Cout) {
  constexpr int K = 1024;
  constexpr int nbn = N_DIM / 128;
  __shared__ unsigned short a_lds[128 * 32];
  __shared__ unsigned short b_lds[128 * 32];
  const int t = threadIdx.x;
  const int w = t >> 6, l = t & 63;
  const int lrow = l & 15, lch = l >> 4;
  const int rid = (blockIdx.x & 7) * (8 * nbn) + (blockIdx.x >> 3);  // grid = 64*nbn, %8==0
  const int m0 = (rid / nbn) * 128;
  const int n0 = (rid % nbn) * 128;
  const int wm = (w >> 1) * 64, wn = (w & 1) * 64;

  const int srow = t >> 2;
  const int schk = t & 3;
  const int scol = ((schk ^ (srow & 3)) << 3);
  const unsigned short* aS0 = A  + (size_t)(m0 + srow) * K + scol;
  const unsigned short* aS1 = A  + (size_t)(m0 + 64 + srow) * K + scol;
  const unsigned short* bS0 = Bt + (size_t)(n0 + srow) * K + scol;
  const unsigned short* bS1 = Bt + (size_t)(n0 + 64 + srow) * K + scol;
  unsigned short* aD0 = a_lds + (w * 16) * 32;
  unsigned short* aD1 = a_lds + (64 + w * 16) * 32;
  unsigned short* bD0 = b_lds + (w * 16) * 32;
  unsigned short* bD1 = b_lds + (64 + w * 16) * 32;

  f32x4 acc[4][4] = {};

  for (int k0 = 0; k0 < K; k0 += 32) {
    gload16(aS0 + k0, aD0);
    gload16(aS1 + k0, aD1);
    gload16(bS0 + k0, bD0);
    gload16(bS1 + k0, bD1);
    __syncthreads();
    bf16x8 af[4], bfr[4];
#pragma unroll
    for (int m = 0; m < 4; ++m) {
      int row = wm + m * 16 + lrow;
      af[m] = ld8(a_lds + row * 32 + ((lch ^ (lrow & 3)) << 3));
    }
#pragma unroll
    for (int n = 0; n < 4; ++n) {
      int row = wn + n * 16 + lrow;
      bfr[n] = ld8(b_lds + row * 32 + ((lch ^ (lrow & 3)) << 3));
    }
#pragma unroll
    for (int m = 0; m < 4; ++m)
#pragma unroll
      for (int n = 0; n < 4; ++n)
        acc[m][n] = __builtin_amdgcn_mfma_f32_16x16x32_bf16(af[m], bfr[n], acc[m][n], 0, 0, 0);
    __syncthreads();
  }

#pragma unroll
  for (int m = 0; m < 4; ++m) {
    const int grow0 = m0 + wm + m * 16 + lch * 4;
#pragma unroll
    for (int n = 0; n < 4; ++n) {
      const int gcol = n0 + wn + n * 16 + lrow;
#pragma unroll
      for (int r = 0; r < 4; ++r)
        Cout[(size_t)(grow0 + r) * N_DIM + gcol] = acc[m][n][r];
    }
  }
}

// ---------------------------------------------------------------------------
// Kernel 3b: fused QKV GEMM + RoPE + split (XCD-remapped).
// ---------------------------------------------------------------------------
__global__ __launch_bounds__(256)
void gemm_qkv_rope_kernel(const unsigned short* __restrict__ A,
                          const unsigned short* __restrict__ Bt,
                          const float* __restrict__ cosb,
                          const float* __restrict__ sinb,
                          unsigned short* __restrict__ Qo,
                          unsigned short* __restrict__ Ko,
                          unsigned short* __restrict__ Vo) {
  constexpr int K = 1024;
  constexpr int nbn = 24;
  __shared__ unsigned short a_lds[128 * 32];
  __shared__ unsigned short b_lds[128 * 32];
  const int t = threadIdx.x;
  const int w = t >> 6, l = t & 63;
  const int lrow = l & 15, lch = l >> 4;
  const int rid = (blockIdx.x & 7) * 192 + (blockIdx.x >> 3);   // 1536 = 8*192
  const int m0 = (rid / nbn) * 128;
  const int n0 = (rid % nbn) * 128;
  const int wm = (w >> 1) * 64;

  const int srow = t >> 2;
  const int schk = t & 3;
  const int scol = ((schk ^ (srow & 3)) << 3);
  const unsigned short* aS0 = A  + (size_t)(m0 + srow) * K + scol;
  const unsigned short* aS1 = A  + (size_t)(m0 + 64 + srow) * K + scol;
  const unsigned short* bS0 = Bt + (size_t)(n0 + srow) * K + scol;
  const unsigned short* bS1 = Bt + (size_t)(n0 + 64 + srow) * K + scol;
  unsigned short* aD0 = a_lds + (w * 16) * 32;
  unsigned short* aD1 = a_lds + (64 + w * 16) * 32;
  unsigned short* bD0 = b_lds + (w * 16) * 32;
  unsigned short* bD1 = b_lds + (64 + w * 16) * 32;

  f32x4 acc[4][4] = {};

  for (int k0 = 0; k0 < K; k0 += 32) {
    gload16(aS0 + k0, aD0);
    gload16(aS1 + k0, aD1);
    gload16(bS0 + k0, bD0);
    gload16(bS1 + k0, bD1);
    __syncthreads();
    bf16x8 af[4], bfr[4];
#pragma unroll
    for (int m = 0; m < 4; ++m) {
      int row = wm + m * 16 + lrow;
      af[m] = ld8(a_lds + row * 32 + ((lch ^ (lrow & 3)) << 3));
    }
#pragma unroll
    for (int n = 0; n < 4; ++n) {
      int row = (w & 1) * 64 + n * 16 + lrow;
      bfr[n] = ld8(b_lds + row * 32 + ((lch ^ (lrow & 3)) << 3));
    }
#pragma unroll
    for (int m = 0; m < 4; ++m)
#pragma unroll
      for (int n = 0; n < 4; ++n)
        acc[m][n] = __builtin_amdgcn_mfma_f32_16x16x32_bf16(af[m], bfr[n], acc[m][n], 0, 0, 0);
    __syncthreads();
  }

  // ---- fused epilogue ----
  const int b = m0 >> 11;
  const int sbase = (m0 & 2047) + wm;
  const int region = n0 >> 10;                  // 0=Q, 1=K, 2=V
  const int h = ((n0 & 1023) >> 6) + (w & 1);   // wave-uniform head

  if (region < 2) {
    const float qs = (region == 0) ? 0.180336880f : 1.0f;   // 1/8*log2e for Q
    unsigned short* dst = (region == 0 ? Qo : Ko) + (size_t)(b * 16 + h) * 2048 * 64;
#pragma unroll
    for (int m = 0; m < 4; ++m) {
#pragma unroll
      for (int r = 0; r < 4; ++r) {
        const int sg = sbase + m * 16 + lch * 4 + r;
        const float* crow = cosb + (size_t)sg * 64;
        const float* srow2 = sinb + (size_t)sg * 64;
        unsigned short* drow = dst + (size_t)sg * 64;
#pragma unroll
        for (int np = 0; np < 2; ++np) {
          const int d0 = np * 16 + lrow;
          const int d1 = d0 + 32;
          const float v0 = acc[m][np][r];
          const float v1 = acc[m][np + 2][r];
          const float r0 = v0 * crow[d0] - v1 * srow2[d0];
          const float r1 = v1 * crow[d1] + v0 * srow2[d1];
          drow[d0] = f2bf(r0 * qs);
          drow[d1] = f2bf(r1 * qs);
        }
      }
    }
  } else {
    unsigned short* dst = Vo + (size_t)(b * 16 + h) * 64 * 2048;
#pragma unroll
    for (int m = 0; m < 4; ++m) {
      const int sg0 = sbase + m * 16 + lch * 4;
#pragma unroll
      for (int np = 0; np < 4; ++np) {
        const int d = np * 16 + lrow;
        alignas(8) unsigned short o4[4];
#pragma unroll
        for (int r = 0; r < 4; ++r) o4[r] = f2bf(acc[m][np][r]);
        *(ushort4*)(dst + (size_t)d * 2048 + sg0) = *(ushort4*)o4;
      }
    }
  }
}

// ---------------------------------------------------------------------------
// Kernel 4: merged mask prep — flag scan in regs; early-exit when all-zero;
// otherwise retile via LDS. flg[(b*32+kvt)*32+qc]; mrs bf16 * log2e.
// ---------------------------------------------------------------------------
__global__ __launch_bounds__(256)
void mask_prep_kernel(const float* __restrict__ mask, unsigned short* __restrict__ mrs,
                      unsigned char* __restrict__ flg) {
  const int bid = blockIdx.x;
  const int kvt = bid & 31, qc = (bid >> 5) & 31, b = bid >> 10;
  const int t = threadIdx.x;
  const int r = t >> 2, c0 = (t & 3) * 16;
  const float* src = mask + (size_t)b * (2048ull * 2048) + (size_t)(qc * 64 + r) * 2048 + kvt * 64 + c0;
  float4 v4[4];
  uint32_t orbits = 0;
#pragma unroll
  for (int i = 0; i < 4; ++i) {
    v4[i] = *(const float4*)(src + i * 4);
    orbits |= __float_as_uint(v4[i].x) | __float_as_uint(v4[i].y) |
              __float_as_uint(v4[i].z) | __float_as_uint(v4[i].w);
  }
  const int nz = __syncthreads_or(orbits != 0u);
  if (t == 0) flg[(size_t)(b * 32 + kvt) * 32 + qc] = (unsigned char)(nz != 0);
  if (!nz) return;                       // uniform across block

  __shared__ float tile[64][72];
#pragma unroll
  for (int i = 0; i < 4; ++i) *(float4*)&tile[r][c0 + i * 4] = v4[i];
  __syncthreads();
  const int cid = t >> 5;
  const int n = cid >> 2, jj = (cid >> 1) & 1, hi = cid & 1;
  const int qq0 = (t & 31) * 2;
  const int cb = n * 32 + jj * 16 + hi * 4;
  unsigned short* dst = mrs + (((size_t)(b * 32 + kvt) * 8 + cid) * 2048 + qc * 64) * 8;
#pragma unroll
  for (int qo = 0; qo < 2; ++qo) {
    const int q = qq0 + qo;
    alignas(16) unsigned short o8[8];
#pragma unroll
    for (int v = 0; v < 8; ++v) {
      const int col = cb + (v >> 2) * 8 + (v & 3);
      o8[v] = f2bf(tile[q][col] * 1.44269504f);
    }
    *(uint4*)(dst + (size_t)q * 8) = *(uint4*)o8;
  }
}

// ---------------------------------------------------------------------------
// Kernel 5: flash attention v7b — v7 (proven 101us) + opaque-zero C-init on
// the lean path (deletes 32 v_mov zero-inits per tile; proven inside v12).
// ---------------------------------------------------------------------------
__global__ __launch_bounds__(256)
void attn_kernel(const unsigned short* __restrict__ Q,
                 const unsigned short* __restrict__ Kg,
                 const unsigned short* __restrict__ Vt,
                 const unsigned short* __restrict__ mrs,
                 const unsigned char* __restrict__ flg,
                 unsigned short* __restrict__ O) {
  const int t = threadIdx.x, w = t >> 6, l = t & 63;
  const int lq = l & 31, hi = l >> 5;
  const int bid = blockIdx.x;
  const int x = bid & 7, y = bid >> 3;           // XCD-grouped mapping
  const int bh = x * 8 + (y & 7), qb = y >> 3;
  const int b = bh >> 4, h = bh & 15;
  const int q0 = qb * 128 + w * 32;

  const unsigned short* Qb = Q  + (size_t)bh * (2048 * 64);
  const unsigned short* Kb = Kg + (size_t)bh * (2048 * 64);
  const unsigned short* Vb = Vt + (size_t)bh * (64 * 2048);
  const unsigned short* ml = mrs + (size_t)b * 4194304 + (size_t)hi * 16384 + (size_t)(q0 + lq) * 8;
  const unsigned char* fb = flg + (size_t)(b * 32) * 32 + qb * 2;  // + kvt*32

  __shared__ unsigned short k_lds[2][64 * 64];
  __shared__ unsigned short v_lds[2][64 * 64];

  bf16x8 qf[4];
  {
    const unsigned short* qp = Qb + (size_t)(q0 + lq) * 64 + hi * 8;
#pragma unroll
    for (int c = 0; c < 4; ++c) qf[c] = ld8(qp + c * 16);
  }
  bf16x8 ones;
  {
    const uint4 ou = { 0x3F803F80u, 0x3F803F80u, 0x3F803F80u, 0x3F803F80u };
    ones = __builtin_bit_cast(bf16x8, ou);
  }
  // opaque zero C-register: compiler cannot re-materialize -> no per-tile init
  f32x16 zreg = {};
  asm("" : "+v"(zreg));

  const int srow = t >> 2, sl0 = (t & 3) * 2, sl1 = sl0 + 1;
  const unsigned short* ks = Kb + (size_t)srow * 64 + sl0 * 8;
  const unsigned short* vs = Vb + (size_t)srow * 2048 + sl0 * 8;
  const int wd0 = srow * 64 + ((sl0 ^ (srow & 7)) << 3);
  const int wd1 = srow * 64 + ((sl1 ^ (srow & 7)) << 3);

  uint4 ka0 = *(const uint4*)ks;
  uint4 ka1 = *(const uint4*)(ks + 8);
  uint4 va0 = *(const uint4*)vs;
  uint4 va1 = *(const uint4*)(vs + 8);
  *(uint4*)(k_lds[0] + wd0) = ka0;
  *(uint4*)(k_lds[0] + wd1) = ka1;
  *(uint4*)(v_lds[0] + wd0) = va0;
  *(uint4*)(v_lds[0] + wd1) = va1;

  f32x16 ot0 = {}, ot1 = {};
  f32x16 st_sum = {};                // all rows = sum_kv P[q]; l = st_sum[0]
  int cur = 0;
  const int lsw = lq & 7;

  uint4 mA[4], mB[4];

  auto do_tile = [&](int kv0, uint4 (&mcur)[4], uint4 (&mnext)[4],
                     bool hm, bool hmn) {
    __syncthreads();   // buf[cur] ready
    const bool more = (kv0 + 64) < 2048;
    if (more) {
      ka0 = *(const uint4*)(ks + (size_t)(kv0 + 64) * 64);
      ka1 = *(const uint4*)(ks + (size_t)(kv0 + 64) * 64 + 8);
      va0 = *(const uint4*)(vs + kv0 + 64);
      va1 = *(const uint4*)(vs + kv0 + 64 + 8);
      if (hmn) {
        const unsigned short* mp = ml + (size_t)(kv0 + 64) * 2048;
#pragma unroll
        for (int c2 = 0; c2 < 4; ++c2) mnext[c2] = *(const uint4*)(mp + c2 * 32768);
      }
    }

    // QK^T — first MFMA pair consumes either the mask unpack (masked path)
    // or the opaque zero register (lean path, no 32 v_movs)
    const unsigned short* kb = k_lds[cur];
    f32x16 st0, st1;
    __builtin_amdgcn_s_setprio(1);
    if (hm) {
#pragma unroll
      for (int jj = 0; jj < 2; ++jj) {
        const uint4 u0 = mcur[jj];
        const uint4 u1 = mcur[2 + jj];
#pragma unroll
        for (int wv = 0; wv < 4; ++wv) {
          const uint32_t w0 = ((const uint32_t*)&u0)[wv];
          const uint32_t w1 = ((const uint32_t*)&u1)[wv];
          st0[jj * 8 + wv * 2]     = u2f(w0 << 16);
          st0[jj * 8 + wv * 2 + 1] = u2f(w0 & 0xffff0000u);
          st1[jj * 8 + wv * 2]     = u2f(w1 << 16);
          st1[jj * 8 + wv * 2 + 1] = u2f(w1 & 0xffff0000u);
        }
      }
      const int so = ((hi ^ lsw) << 3);
      const bf16x8 kf0 = ld8(kb + lq * 64 + so);
      const bf16x8 kf1 = ld8(kb + (32 + lq) * 64 + so);
      st0 = __builtin_amdgcn_mfma_f32_32x32x16_bf16(kf0, qf[0], st0, 0, 0, 0);
      st1 = __builtin_amdgcn_mfma_f32_32x32x16_bf16(kf1, qf[0], st1, 0, 0, 0);
    } else {
      const int so = ((hi ^ lsw) << 3);
      const bf16x8 kf0 = ld8(kb + lq * 64 + so);
      const bf16x8 kf1 = ld8(kb + (32 + lq) * 64 + so);
      st0 = __builtin_amdgcn_mfma_f32_32x32x16_bf16(kf0, qf[0], zreg, 0, 0, 0);
      st1 = __builtin_amdgcn_mfma_f32_32x32x16_bf16(kf1, qf[0], zreg, 0, 0, 0);
    }
#pragma unroll
    for (int c = 1; c < 4; ++c) {
      const int so = (((2 * c + hi) ^ lsw) << 3);
      const bf16x8 kf0 = ld8(kb + lq * 64 + so);
      const bf16x8 kf1 = ld8(kb + (32 + lq) * 64 + so);
      st0 = __builtin_amdgcn_mfma_f32_32x32x16_bf16(kf0, qf[c], st0, 0, 0, 0);
      st1 = __builtin_amdgcn_mfma_f32_32x32x16_bf16(kf1, qf[c], st1, 0, 0, 0);
    }
    __builtin_amdgcn_s_setprio(0);

    // absolute-scale P = exp2(st); no max, no rescale, no VALU sum
#pragma unroll
    for (int r = 0; r < 16; ++r) {
      st0[r] = exp2b(st0[r]);
      st1[r] = exp2b(st1[r]);
    }

    // P^T B-fragments in-register (T12)
    bf16x8 pa[4];
#pragma unroll
    for (int c = 0; c < 4; ++c) {
      const int e8 = (c & 1) * 8;
      uint32_t A01, B01, A23, B23;
      if (c < 2) {
        A01 = cvtpk(st0[e8 + 0], st0[e8 + 1]);
        B01 = cvtpk(st0[e8 + 4], st0[e8 + 5]);
        A23 = cvtpk(st0[e8 + 2], st0[e8 + 3]);
        B23 = cvtpk(st0[e8 + 6], st0[e8 + 7]);
      } else {
        A01 = cvtpk(st1[e8 + 0], st1[e8 + 1]);
        B01 = cvtpk(st1[e8 + 4], st1[e8 + 5]);
        A23 = cvtpk(st1[e8 + 2], st1[e8 + 3]);
        B23 = cvtpk(st1[e8 + 6], st1[e8 + 7]);
      }
      permswap(A01, B01);
      permswap(A23, B23);
      const uint4 pw = { A01, A23, B01, B23 };
      pa[c] = __builtin_bit_cast(bf16x8, pw);
    }

    // stage next tile (write-late; global loads issued at tile top)
    if (more) {
      unsigned short* kn = k_lds[cur ^ 1];
      unsigned short* vn = v_lds[cur ^ 1];
      *(uint4*)(kn + wd0) = ka0;
      *(uint4*)(kn + wd1) = ka1;
      *(uint4*)(vn + wd0) = va0;
      *(uint4*)(vn + wd1) = va1;
    }

    // O^T += V^T x P^T; denominator via ones-MFMA (rows all = sum_kv P[q])
    const unsigned short* vb = v_lds[cur];
    __builtin_amdgcn_s_setprio(1);
#pragma unroll
    for (int c = 0; c < 4; ++c) {
      const int so = (((2 * c + hi) ^ lsw) << 3);
      const bf16x8 vf0 = ld8(vb + lq * 64 + so);
      const bf16x8 vf1 = ld8(vb + (32 + lq) * 64 + so);
      ot0 = __builtin_amdgcn_mfma_f32_32x32x16_bf16(vf0, pa[c], ot0, 0, 0, 0);
      ot1 = __builtin_amdgcn_mfma_f32_32x32x16_bf16(vf1, pa[c], ot1, 0, 0, 0);
      st_sum = __builtin_amdgcn_mfma_f32_32x32x16_bf16(ones, pa[c], st_sum, 0, 0, 0);
    }
    __builtin_amdgcn_s_setprio(0);
    cur ^= 1;
  };

  // block-level mask specialization: OR of flags over all kv-tiles
  unsigned int bm = 0;
  for (int kvt = 0; kvt < 32; ++kvt) bm |= fb[kvt * 32] | fb[kvt * 32 + 1];

  if (bm == 0) {
    for (int kv0 = 0; kv0 < 2048; kv0 += 128) {
      do_tile(kv0, mA, mB, false, false);
      do_tile(kv0 + 64, mB, mA, false, false);
    }
  } else {
    bool hmA = (fb[0] | fb[1]) != 0;
    if (hmA) {
#pragma unroll
      for (int c2 = 0; c2 < 4; ++c2) mA[c2] = *(const uint4*)(ml + c2 * 32768);
    }
    bool hmB = false;
    for (int kv0 = 0; kv0 < 2048; kv0 += 128) {
      const int tB = (kv0 >> 6) + 1;
      hmB = (kv0 + 64 < 2048) && ((fb[tB * 32] | fb[tB * 32 + 1]) != 0);
      do_tile(kv0, mA, mB, hmA, hmB);
      const int tA = tB + 1;
      hmA = (kv0 + 128 < 2048) && ((fb[tA * 32] | fb[tA * 32 + 1]) != 0);
      do_tile(kv0 + 64, mB, mA, hmB, hmA);
    }
  }

  // epilogue: l = st_sum[0] (all rows identical per q-column)
  const float inv = 1.0f / st_sum[0];
  unsigned short* ob = O + ((size_t)(b * 2048 + q0 + lq) * 16 + h) * 64 + hi * 4;
#pragma unroll
  for (int td = 0; td < 2; ++td) {
#pragma unroll
    for (int rr = 0; rr < 4; ++rr) {
      ushort4 ov;
      if (td == 0) {
        ov.x = f2bf(ot0[rr * 4 + 0] * inv);
        ov.y = f2bf(ot0[rr * 4 + 1] * inv);
        ov.z = f2bf(ot0[rr * 4 + 2] * inv);
        ov.w = f2bf(ot0[rr * 4 + 3] * inv);
      } else {
        ov.x = f2bf(ot1[rr * 4 + 0] * inv);
        ov.y = f2bf(ot1[rr * 4 + 1] * inv);
        ov.z = f2bf(ot1[rr * 4 + 2] * inv);
        ov.w = f2bf(ot1[rr * 4 + 3] * inv);
      }
      *(ushort4*)(ob + td * 32 + rr * 8) = ov;
    }
  }
}

// ---------------------------------------------------------------------------
extern "C" void kernel_launch(void* const* d_in, const int* in_sizes, int n_in,
                              void* d_out, int out_size, void* d_ws, size_t ws_size,
                              hipStream_t stream) {
  (void)in_sizes; (void)n_in; (void)out_size; (void)ws_size;
  const float* x     = (const float*)d_in[0];
  const float* mask  = (const float*)d_in[1];
  const float* cosb  = (const float*)d_in[2];
  const float* sinb  = (const float*)d_in[3];
  const float* gamma = (const float*)d_in[4];
  const float* w_qkv = (const float*)d_in[5];
  const float* w_o   = (const float*)d_in[6];

  char* ws = (char*)d_ws;
  unsigned short* x_bf   = (unsigned short*)(ws);                 // 16,777,216 B
  unsigned short* wqkvT  = (unsigned short*)(ws + 16777216);      //  6,291,456 B
  unsigned short* woT    = (unsigned short*)(ws + 23068672);      //  2,097,152 B
  unsigned short* mask_rs = (unsigned short*)(ws + 25165824);     // 33,554,432 B
  unsigned char*  flags   = (unsigned char*)(ws + 25165824 + 33554432);
  unsigned short* q_r    = (unsigned short*)(ws + 75497472);      // 16,777,216 B
  unsigned short* k_r    = (unsigned short*)(ws + 92274688);      // 16,777,216 B
  unsigned short* v_t    = (unsigned short*)(ws + 109051904);     // 16,777,216 B
  unsigned short* attn   = (unsigned short*)(ws + 125829120);     // 16,777,216 B

  transpose_both_kernel<<<dim3(768 + 256), dim3(256), 0, stream>>>(w_qkv, w_o, wqkvT, woT);
  ln_kernel<<<dim3(8192), dim3(256), 0, stream>>>(x, gamma, x_bf);
  gemm_qkv_rope_kernel<<<dim3(64 * 24), dim3(256), 0, stream>>>(x_bf, wqkvT, cosb, sinb, q_r, k_r, v_t);
  mask_prep_kernel<<<dim3(4096), dim3(256), 0, stream>>>(mask, mask_rs, flags);
  attn_kernel<<<dim3(1024), dim3(256), 0, stream>>>(q_r, k_r, v_t, mask_rs, flags, attn);
  gemm_bt_kernel<1024><<<dim3(64 * 8), dim3(256), 0, stream>>>(attn, woT, (float*)d_out);
}

// Round 19
// 227.065 us; speedup vs baseline: 1.1284x; 1.1284x over previous
//
#include <hip/hip_runtime.h>
#include <stdint.h>

#define DEV __device__ __forceinline__

typedef __bf16 bf16x8 __attribute__((ext_vector_type(8)));
typedef float f32x4 __attribute__((ext_vector_type(4)));
typedef float f32x16 __attribute__((ext_vector_type(16)));

DEV unsigned short f2bf(float f) {
  union { float f; uint32_t u; } c; c.f = f;
  uint32_t u = c.u;
  u += 0x7FFFu + ((u >> 16) & 1u);   // round-to-nearest-even
  return (unsigned short)(u >> 16);
}
DEV float bf2f(unsigned short h) {
  union { uint32_t u; float f; } c; c.u = ((uint32_t)h) << 16;
  return c.f;
}
DEV float u2f(uint32_t u) {
  union { uint32_t u; float f; } c; c.u = u;
  return c.f;
}
DEV bf16x8 ld8(const unsigned short* p) {
  uint4 u = *reinterpret_cast<const uint4*>(p);
  return __builtin_bit_cast(bf16x8, u);
}
DEV uint32_t cvtpk(float lo, float hi) {
  uint32_t r;
  asm("v_cvt_pk_bf16_f32 %0, %1, %2" : "=v"(r) : "v"(lo), "v"(hi));
  return r;
}
// NEW a[32:63] = OLD b[0:31]; NEW b[0:31] = OLD a[32:63]; rest unchanged.
DEV void permswap(uint32_t& a, uint32_t& b) {
  asm("v_permlane32_swap_b32 %0, %1" : "+v"(a), "+v"(b));
}
// exp2 via compiler builtin -> v_exp_f32 with trans-hazard handling
DEV float exp2b(float x) { return __builtin_amdgcn_exp2f(x); }
// async global->LDS, 16B per lane; LDS dest must be wave-uniform-base + lane*16
DEV void gload16(const void* g, void* l) {
  __builtin_amdgcn_global_load_lds((const __attribute__((address_space(1))) void*)g,
                                   (__attribute__((address_space(3))) void*)l, 16, 0, 0);
}

// ---------------------------------------------------------------------------
// Kernel 1: merged weight transpose+cast: w_qkv [1024][3072] and w_o
// [1024][1024] -> bf16 [N][K] in one launch.
// ---------------------------------------------------------------------------
__global__ __launch_bounds__(256)
void transpose_both_kernel(const float* __restrict__ wqkv, const float* __restrict__ wo,
                           unsigned short* __restrict__ oqkv, unsigned short* __restrict__ oo) {
  int bid = blockIdx.x;
  const float* in;
  unsigned short* out;
  int N;
  if (bid < 768) {                 // 16 k-blocks x 48 n-blocks
    in = wqkv; out = oqkv; N = 3072;
  } else {
    bid -= 768; in = wo; out = oo; N = 1024;   // 16 x 16
  }
  const int bk = bid & 15, bn = bid >> 4;
  const int k0 = bk * 64, n0 = bn * 64;
  const int t = threadIdx.x;
  __shared__ float tile[64][65];
#pragma unroll
  for (int i = 0; i < 16; ++i) {
    int idx = t + i * 256;
    int kl = idx >> 6, nl = idx & 63;
    tile[kl][nl] = in[(size_t)(k0 + kl) * N + n0 + nl];
  }
  __syncthreads();
#pragma unroll
  for (int i = 0; i < 16; ++i) {
    int idx = t + i * 256;
    int nl = idx >> 6, kl = idx & 63;
    out[(size_t)(n0 + nl) * 1024 + k0 + kl] = f2bf(tile[kl][nl]);
  }
}

// ---------------------------------------------------------------------------
// Kernel 2: LayerNorm (no beta) f32 -> bf16, one block per row of 1024
// ---------------------------------------------------------------------------
__global__ __launch_bounds__(256)
void ln_kernel(const float* __restrict__ x, const float* __restrict__ gamma,
               unsigned short* __restrict__ y) {
  const int row = blockIdx.x;
  const int t = threadIdx.x;
  const float4 v = reinterpret_cast<const float4*>(x + (size_t)row * 1024)[t];
  float s  = v.x + v.y + v.z + v.w;
  float s2 = v.x * v.x + v.y * v.y + v.z * v.z + v.w * v.w;
#pragma unroll
  for (int off = 1; off < 64; off <<= 1) {
    s  += __shfl_xor(s, off);
    s2 += __shfl_xor(s2, off);
  }
  __shared__ float red[8];
  const int w = t >> 6, lane = t & 63;
  if (lane == 0) { red[w] = s; red[4 + w] = s2; }
  __syncthreads();
  s  = red[0] + red[1] + red[2] + red[3];
  s2 = red[4] + red[5] + red[6] + red[7];
  const float mu = s * (1.0f / 1024.0f);
  const float var = s2 * (1.0f / 1024.0f) - mu * mu;
  const float rstd = rsqrtf(var + 1e-5f);
  const float4 g = reinterpret_cast<const float4*>(gamma)[t];
  ushort4 o;
  o.x = f2bf((v.x - mu) * rstd * g.x);
  o.y = f2bf((v.y - mu) * rstd * g.y);
  o.z = f2bf((v.z - mu) * rstd * g.z);
  o.w = f2bf((v.w - mu) * rstd * g.w);
  reinterpret_cast<ushort4*>(y + (size_t)row * 1024)[t] = o;
}

// ---------------------------------------------------------------------------
// Kernel 3: bf16 GEMM, A[M][1024] x Bt[N][1024]^T -> C[M][N] (f32 out).
// 128x128 tile, BK=32, 4 waves, 16x16x32 MFMA, global_load_lds staging.
// XCD-bijective block remap (T1). Used for the output projection.
// ---------------------------------------------------------------------------
template<int N_DIM>
__global__ __launch_bounds__(256)
void gemm_bt_kernel(const unsigned short* __restrict__ A,
                    const unsigned short* __restrict__ Bt,
                    float* __restrict__ Cout) {
  constexpr int K = 1024;
  constexpr int nbn = N_DIM / 128;
  __shared__ unsigned short a_lds[128 * 32];
  __shared__ unsigned short b_lds[128 * 32];
  const int t = threadIdx.x;
  const int w = t >> 6, l = t & 63;
  const int lrow = l & 15, lch = l >> 4;
  const int rid = (blockIdx.x & 7) * (8 * nbn) + (blockIdx.x >> 3);  // grid = 64*nbn, %8==0
  const int m0 = (rid / nbn) * 128;
  const int n0 = (rid % nbn) * 128;
  const int wm = (w >> 1) * 64, wn = (w & 1) * 64;

  const int srow = t >> 2;
  const int schk = t & 3;
  const int scol = ((schk ^ (srow & 3)) << 3);
  const unsigned short* aS0 = A  + (size_t)(m0 + srow) * K + scol;
  const unsigned short* aS1 = A  + (size_t)(m0 + 64 + srow) * K + scol;
  const unsigned short* bS0 = Bt + (size_t)(n0 + srow) * K + scol;
  const unsigned short* bS1 = Bt + (size_t)(n0 + 64 + srow) * K + scol;
  unsigned short* aD0 = a_lds + (w * 16) * 32;
  unsigned short* aD1 = a_lds + (64 + w * 16) * 32;
  unsigned short* bD0 = b_lds + (w * 16) * 32;
  unsigned short* bD1 = b_lds + (64 + w * 16) * 32;

  f32x4 acc[4][4] = {};

  for (int k0 = 0; k0 < K; k0 += 32) {
    gload16(aS0 + k0, aD0);
    gload16(aS1 + k0, aD1);
    gload16(bS0 + k0, bD0);
    gload16(bS1 + k0, bD1);
    __syncthreads();
    bf16x8 af[4], bfr[4];
#pragma unroll
    for (int m = 0; m < 4; ++m) {
      int row = wm + m * 16 + lrow;
      af[m] = ld8(a_lds + row * 32 + ((lch ^ (lrow & 3)) << 3));
    }
#pragma unroll
    for (int n = 0; n < 4; ++n) {
      int row = wn + n * 16 + lrow;
      bfr[n] = ld8(b_lds + row * 32 + ((lch ^ (lrow & 3)) << 3));
    }
#pragma unroll
    for (int m = 0; m < 4; ++m)
#pragma unroll
      for (int n = 0; n < 4; ++n)
        acc[m][n] = __builtin_amdgcn_mfma_f32_16x16x32_bf16(af[m], bfr[n], acc[m][n], 0, 0, 0);
    __syncthreads();
  }

#pragma unroll
  for (int m = 0; m < 4; ++m) {
    const int grow0 = m0 + wm + m * 16 + lch * 4;
#pragma unroll
    for (int n = 0; n < 4; ++n) {
      const int gcol = n0 + wn + n * 16 + lrow;
#pragma unroll
      for (int r = 0; r < 4; ++r)
        Cout[(size_t)(grow0 + r) * N_DIM + gcol] = acc[m][n][r];
    }
  }
}

// ---------------------------------------------------------------------------
// Kernel 3b: fused QKV GEMM + RoPE + split (XCD-remapped).
// ---------------------------------------------------------------------------
__global__ __launch_bounds__(256)
void gemm_qkv_rope_kernel(const unsigned short* __restrict__ A,
                          const unsigned short* __restrict__ Bt,
                          const float* __restrict__ cosb,
                          const float* __restrict__ sinb,
                          unsigned short* __restrict__ Qo,
                          unsigned short* __restrict__ Ko,
                          unsigned short* __restrict__ Vo) {
  constexpr int K = 1024;
  constexpr int nbn = 24;
  __shared__ unsigned short a_lds[128 * 32];
  __shared__ unsigned short b_lds[128 * 32];
  const int t = threadIdx.x;
  const int w = t >> 6, l = t & 63;
  const int lrow = l & 15, lch = l >> 4;
  const int rid = (blockIdx.x & 7) * 192 + (blockIdx.x >> 3);   // 1536 = 8*192
  const int m0 = (rid / nbn) * 128;
  const int n0 = (rid % nbn) * 128;
  const int wm = (w >> 1) * 64;

  const int srow = t >> 2;
  const int schk = t & 3;
  const int scol = ((schk ^ (srow & 3)) << 3);
  const unsigned short* aS0 = A  + (size_t)(m0 + srow) * K + scol;
  const unsigned short* aS1 = A  + (size_t)(m0 + 64 + srow) * K + scol;
  const unsigned short* bS0 = Bt + (size_t)(n0 + srow) * K + scol;
  const unsigned short* bS1 = Bt + (size_t)(n0 + 64 + srow) * K + scol;
  unsigned short* aD0 = a_lds + (w * 16) * 32;
  unsigned short* aD1 = a_lds + (64 + w * 16) * 32;
  unsigned short* bD0 = b_lds + (w * 16) * 32;
  unsigned short* bD1 = b_lds + (64 + w * 16) * 32;

  f32x4 acc[4][4] = {};

  for (int k0 = 0; k0 < K; k0 += 32) {
    gload16(aS0 + k0, aD0);
    gload16(aS1 + k0, aD1);
    gload16(bS0 + k0, bD0);
    gload16(bS1 + k0, bD1);
    __syncthreads();
    bf16x8 af[4], bfr[4];
#pragma unroll
    for (int m = 0; m < 4; ++m) {
      int row = wm + m * 16 + lrow;
      af[m] = ld8(a_lds + row * 32 + ((lch ^ (lrow & 3)) << 3));
    }
#pragma unroll
    for (int n = 0; n < 4; ++n) {
      int row = (w & 1) * 64 + n * 16 + lrow;
      bfr[n] = ld8(b_lds + row * 32 + ((lch ^ (lrow & 3)) << 3));
    }
#pragma unroll
    for (int m = 0; m < 4; ++m)
#pragma unroll
      for (int n = 0; n < 4; ++n)
        acc[m][n] = __builtin_amdgcn_mfma_f32_16x16x32_bf16(af[m], bfr[n], acc[m][n], 0, 0, 0);
    __syncthreads();
  }

  // ---- fused epilogue ----
  const int b = m0 >> 11;
  const int sbase = (m0 & 2047) + wm;
  const int region = n0 >> 10;                  // 0=Q, 1=K, 2=V
  const int h = ((n0 & 1023) >> 6) + (w & 1);   // wave-uniform head

  if (region < 2) {
    const float qs = (region == 0) ? 0.180336880f : 1.0f;   // 1/8*log2e for Q
    unsigned short* dst = (region == 0 ? Qo : Ko) + (size_t)(b * 16 + h) * 2048 * 64;
#pragma unroll
    for (int m = 0; m < 4; ++m) {
#pragma unroll
      for (int r = 0; r < 4; ++r) {
        const int sg = sbase + m * 16 + lch * 4 + r;
        const float* crow = cosb + (size_t)sg * 64;
        const float* srow2 = sinb + (size_t)sg * 64;
        unsigned short* drow = dst + (size_t)sg * 64;
#pragma unroll
        for (int np = 0; np < 2; ++np) {
          const int d0 = np * 16 + lrow;
          const int d1 = d0 + 32;
          const float v0 = acc[m][np][r];
          const float v1 = acc[m][np + 2][r];
          const float r0 = v0 * crow[d0] - v1 * srow2[d0];
          const float r1 = v1 * crow[d1] + v0 * srow2[d1];
          drow[d0] = f2bf(r0 * qs);
          drow[d1] = f2bf(r1 * qs);
        }
      }
    }
  } else {
    unsigned short* dst = Vo + (size_t)(b * 16 + h) * 64 * 2048;
#pragma unroll
    for (int m = 0; m < 4; ++m) {
      const int sg0 = sbase + m * 16 + lch * 4;
#pragma unroll
      for (int np = 0; np < 4; ++np) {
        const int d = np * 16 + lrow;
        alignas(8) unsigned short o4[4];
#pragma unroll
        for (int r = 0; r < 4; ++r) o4[r] = f2bf(acc[m][np][r]);
        *(ushort4*)(dst + (size_t)d * 2048 + sg0) = *(ushort4*)o4;
      }
    }
  }
}

// ---------------------------------------------------------------------------
// Kernel 4: merged mask prep — flag scan in regs; early-exit when all-zero;
// otherwise retile via LDS. flg[(b*32+kvt)*32+qc]; mrs bf16 * log2e.
// ---------------------------------------------------------------------------
__global__ __launch_bounds__(256)
void mask_prep_kernel(const float* __restrict__ mask, unsigned short* __restrict__ mrs,
                      unsigned char* __restrict__ flg) {
  const int bid = blockIdx.x;
  const int kvt = bid & 31, qc = (bid >> 5) & 31, b = bid >> 10;
  const int t = threadIdx.x;
  const int r = t >> 2, c0 = (t & 3) * 16;
  const float* src = mask + (size_t)b * (2048ull * 2048) + (size_t)(qc * 64 + r) * 2048 + kvt * 64 + c0;
  float4 v4[4];
  uint32_t orbits = 0;
#pragma unroll
  for (int i = 0; i < 4; ++i) {
    v4[i] = *(const float4*)(src + i * 4);
    orbits |= __float_as_uint(v4[i].x) | __float_as_uint(v4[i].y) |
              __float_as_uint(v4[i].z) | __float_as_uint(v4[i].w);
  }
  const int nz = __syncthreads_or(orbits != 0u);
  if (t == 0) flg[(size_t)(b * 32 + kvt) * 32 + qc] = (unsigned char)(nz != 0);
  if (!nz) return;                       // uniform across block

  __shared__ float tile[64][72];
#pragma unroll
  for (int i = 0; i < 4; ++i) *(float4*)&tile[r][c0 + i * 4] = v4[i];
  __syncthreads();
  const int cid = t >> 5;
  const int n = cid >> 2, jj = (cid >> 1) & 1, hi = cid & 1;
  const int qq0 = (t & 31) * 2;
  const int cb = n * 32 + jj * 16 + hi * 4;
  unsigned short* dst = mrs + (((size_t)(b * 32 + kvt) * 8 + cid) * 2048 + qc * 64) * 8;
#pragma unroll
  for (int qo = 0; qo < 2; ++qo) {
    const int q = qq0 + qo;
    alignas(16) unsigned short o8[8];
#pragma unroll
    for (int v = 0; v < 8; ++v) {
      const int col = cb + (v >> 2) * 8 + (v & 3);
      o8[v] = f2bf(tile[q][col] * 1.44269504f);
    }
    *(uint4*)(dst + (size_t)q * 8) = *(uint4*)o8;
  }
}

// ---------------------------------------------------------------------------
// Kernel 5 (exact R17 v7, proven 101.8us): flash attention — swapped QK^T,
// 32x32x16 MFMA, exp2 absolute-scale softmax, ones-MFMA denominator,
// block-level mask specialization, double-buffered K/V LDS, setprio.
// NOTE: plain {} C-init, NOT opaque-zero — R18 proved pinning 16 VGPRs costs
// an occupancy cliff (128->152 VGPR, 19.7%->11%, +35us).
// ---------------------------------------------------------------------------
__global__ __launch_bounds__(256)
void attn_kernel(const unsigned short* __restrict__ Q,
                 const unsigned short* __restrict__ Kg,
                 const unsigned short* __restrict__ Vt,
                 const unsigned short* __restrict__ mrs,
                 const unsigned char* __restrict__ flg,
                 unsigned short* __restrict__ O) {
  const int t = threadIdx.x, w = t >> 6, l = t & 63;
  const int lq = l & 31, hi = l >> 5;
  const int bid = blockIdx.x;
  const int x = bid & 7, y = bid >> 3;           // XCD-grouped mapping
  const int bh = x * 8 + (y & 7), qb = y >> 3;
  const int b = bh >> 4, h = bh & 15;
  const int q0 = qb * 128 + w * 32;

  const unsigned short* Qb = Q  + (size_t)bh * (2048 * 64);
  const unsigned short* Kb = Kg + (size_t)bh * (2048 * 64);
  const unsigned short* Vb = Vt + (size_t)bh * (64 * 2048);
  const unsigned short* ml = mrs + (size_t)b * 4194304 + (size_t)hi * 16384 + (size_t)(q0 + lq) * 8;
  const unsigned char* fb = flg + (size_t)(b * 32) * 32 + qb * 2;  // + kvt*32

  __shared__ unsigned short k_lds[2][64 * 64];
  __shared__ unsigned short v_lds[2][64 * 64];

  bf16x8 qf[4];
  {
    const unsigned short* qp = Qb + (size_t)(q0 + lq) * 64 + hi * 8;
#pragma unroll
    for (int c = 0; c < 4; ++c) qf[c] = ld8(qp + c * 16);
  }
  bf16x8 ones;
  {
    const uint4 ou = { 0x3F803F80u, 0x3F803F80u, 0x3F803F80u, 0x3F803F80u };
    ones = __builtin_bit_cast(bf16x8, ou);
  }

  const int srow = t >> 2, sl0 = (t & 3) * 2, sl1 = sl0 + 1;
  const unsigned short* ks = Kb + (size_t)srow * 64 + sl0 * 8;
  const unsigned short* vs = Vb + (size_t)srow * 2048 + sl0 * 8;
  const int wd0 = srow * 64 + ((sl0 ^ (srow & 7)) << 3);
  const int wd1 = srow * 64 + ((sl1 ^ (srow & 7)) << 3);

  uint4 ka0 = *(const uint4*)ks;
  uint4 ka1 = *(const uint4*)(ks + 8);
  uint4 va0 = *(const uint4*)vs;
  uint4 va1 = *(const uint4*)(vs + 8);
  *(uint4*)(k_lds[0] + wd0) = ka0;
  *(uint4*)(k_lds[0] + wd1) = ka1;
  *(uint4*)(v_lds[0] + wd0) = va0;
  *(uint4*)(v_lds[0] + wd1) = va1;

  f32x16 ot0 = {}, ot1 = {};
  f32x16 st_sum = {};                // all rows = sum_kv P[q]; l = st_sum[0]
  int cur = 0;
  const int lsw = lq & 7;

  uint4 mA[4], mB[4];

  auto do_tile = [&](int kv0, uint4 (&mcur)[4], uint4 (&mnext)[4],
                     bool hm, bool hmn) {
    __syncthreads();   // buf[cur] ready
    const bool more = (kv0 + 64) < 2048;
    if (more) {
      ka0 = *(const uint4*)(ks + (size_t)(kv0 + 64) * 64);
      ka1 = *(const uint4*)(ks + (size_t)(kv0 + 64) * 64 + 8);
      va0 = *(const uint4*)(vs + kv0 + 64);
      va1 = *(const uint4*)(vs + kv0 + 64 + 8);
      if (hmn) {
        const unsigned short* mp = ml + (size_t)(kv0 + 64) * 2048;
#pragma unroll
        for (int c2 = 0; c2 < 4; ++c2) mnext[c2] = *(const uint4*)(mp + c2 * 32768);
      }
    }

    // C-init: mask*log2e or zeros
    f32x16 st0 = {}, st1 = {};
    if (hm) {
#pragma unroll
      for (int jj = 0; jj < 2; ++jj) {
        const uint4 u0 = mcur[jj];
        const uint4 u1 = mcur[2 + jj];
#pragma unroll
        for (int wv = 0; wv < 4; ++wv) {
          const uint32_t w0 = ((const uint32_t*)&u0)[wv];
          const uint32_t w1 = ((const uint32_t*)&u1)[wv];
          st0[jj * 8 + wv * 2]     = u2f(w0 << 16);
          st0[jj * 8 + wv * 2 + 1] = u2f(w0 & 0xffff0000u);
          st1[jj * 8 + wv * 2]     = u2f(w1 << 16);
          st1[jj * 8 + wv * 2 + 1] = u2f(w1 & 0xffff0000u);
        }
      }
    }

    // QK^T (C-in = mask or zeros)
    const unsigned short* kb = k_lds[cur];
    __builtin_amdgcn_s_setprio(1);
#pragma unroll
    for (int c = 0; c < 4; ++c) {
      const int so = (((2 * c + hi) ^ lsw) << 3);
      const bf16x8 kf0 = ld8(kb + lq * 64 + so);
      const bf16x8 kf1 = ld8(kb + (32 + lq) * 64 + so);
      st0 = __builtin_amdgcn_mfma_f32_32x32x16_bf16(kf0, qf[c], st0, 0, 0, 0);
      st1 = __builtin_amdgcn_mfma_f32_32x32x16_bf16(kf1, qf[c], st1, 0, 0, 0);
    }
    __builtin_amdgcn_s_setprio(0);

    // absolute-scale P = exp2(st); no max, no rescale, no VALU sum
#pragma unroll
    for (int r = 0; r < 16; ++r) {
      st0[r] = exp2b(st0[r]);
      st1[r] = exp2b(st1[r]);
    }

    // P^T B-fragments in-register (T12)
    bf16x8 pa[4];
#pragma unroll
    for (int c = 0; c < 4; ++c) {
      const int e8 = (c & 1) * 8;
      uint32_t A01, B01, A23, B23;
      if (c < 2) {
        A01 = cvtpk(st0[e8 + 0], st0[e8 + 1]);
        B01 = cvtpk(st0[e8 + 4], st0[e8 + 5]);
        A23 = cvtpk(st0[e8 + 2], st0[e8 + 3]);
        B23 = cvtpk(st0[e8 + 6], st0[e8 + 7]);
      } else {
        A01 = cvtpk(st1[e8 + 0], st1[e8 + 1]);
        B01 = cvtpk(st1[e8 + 4], st1[e8 + 5]);
        A23 = cvtpk(st1[e8 + 2], st1[e8 + 3]);
        B23 = cvtpk(st1[e8 + 6], st1[e8 + 7]);
      }
      permswap(A01, B01);
      permswap(A23, B23);
      const uint4 pw = { A01, A23, B01, B23 };
      pa[c] = __builtin_bit_cast(bf16x8, pw);
    }

    // stage next tile (write-late; global loads issued at tile top)
    if (more) {
      unsigned short* kn = k_lds[cur ^ 1];
      unsigned short* vn = v_lds[cur ^ 1];
      *(uint4*)(kn + wd0) = ka0;
      *(uint4*)(kn + wd1) = ka1;
      *(uint4*)(vn + wd0) = va0;
      *(uint4*)(vn + wd1) = va1;
    }

    // O^T += V^T x P^T; denominator via ones-MFMA (rows all = sum_kv P[q])
    const unsigned short* vb = v_lds[cur];
    __builtin_amdgcn_s_setprio(1);
#pragma unroll
    for (int c = 0; c < 4; ++c) {
      const int so = (((2 * c + hi) ^ lsw) << 3);
      const bf16x8 vf0 = ld8(vb + lq * 64 + so);
      const bf16x8 vf1 = ld8(vb + (32 + lq) * 64 + so);
      ot0 = __builtin_amdgcn_mfma_f32_32x32x16_bf16(vf0, pa[c], ot0, 0, 0, 0);
      ot1 = __builtin_amdgcn_mfma_f32_32x32x16_bf16(vf1, pa[c], ot1, 0, 0, 0);
      st_sum = __builtin_amdgcn_mfma_f32_32x32x16_bf16(ones, pa[c], st_sum, 0, 0, 0);
    }
    __builtin_amdgcn_s_setprio(0);
    cur ^= 1;
  };

  // block-level mask specialization: OR of flags over all kv-tiles
  unsigned int bm = 0;
  for (int kvt = 0; kvt < 32; ++kvt) bm |= fb[kvt * 32] | fb[kvt * 32 + 1];

  if (bm == 0) {
    for (int kv0 = 0; kv0 < 2048; kv0 += 128) {
      do_tile(kv0, mA, mB, false, false);
      do_tile(kv0 + 64, mB, mA, false, false);
    }
  } else {
    bool hmA = (fb[0] | fb[1]) != 0;
    if (hmA) {
#pragma unroll
      for (int c2 = 0; c2 < 4; ++c2) mA[c2] = *(const uint4*)(ml + c2 * 32768);
    }
    bool hmB = false;
    for (int kv0 = 0; kv0 < 2048; kv0 += 128) {
      const int tB = (kv0 >> 6) + 1;
      hmB = (kv0 + 64 < 2048) && ((fb[tB * 32] | fb[tB * 32 + 1]) != 0);
      do_tile(kv0, mA, mB, hmA, hmB);
      const int tA = tB + 1;
      hmA = (kv0 + 128 < 2048) && ((fb[tA * 32] | fb[tA * 32 + 1]) != 0);
      do_tile(kv0 + 64, mB, mA, hmB, hmA);
    }
  }

  // epilogue: l = st_sum[0] (all rows identical per q-column)
  const float inv = 1.0f / st_sum[0];
  unsigned short* ob = O + ((size_t)(b * 2048 + q0 + lq) * 16 + h) * 64 + hi * 4;
#pragma unroll
  for (int td = 0; td < 2; ++td) {
#pragma unroll
    for (int rr = 0; rr < 4; ++rr) {
      ushort4 ov;
      if (td == 0) {
        ov.x = f2bf(ot0[rr * 4 + 0] * inv);
        ov.y = f2bf(ot0[rr * 4 + 1] * inv);
        ov.z = f2bf(ot0[rr * 4 + 2] * inv);
        ov.w = f2bf(ot0[rr * 4 + 3] * inv);
      } else {
        ov.x = f2bf(ot1[rr * 4 + 0] * inv);
        ov.y = f2bf(ot1[rr * 4 + 1] * inv);
        ov.z = f2bf(ot1[rr * 4 + 2] * inv);
        ov.w = f2bf(ot1[rr * 4 + 3] * inv);
      }
      *(ushort4*)(ob + td * 32 + rr * 8) = ov;
    }
  }
}

// ---------------------------------------------------------------------------
extern "C" void kernel_launch(void* const* d_in, const int* in_sizes, int n_in,
                              void* d_out, int out_size, void* d_ws, size_t ws_size,
                              hipStream_t stream) {
  (void)in_sizes; (void)n_in; (void)out_size; (void)ws_size;
  const float* x     = (const float*)d_in[0];
  const float* mask  = (const float*)d_in[1];
  const float* cosb  = (const float*)d_in[2];
  const float* sinb  = (const float*)d_in[3];
  const float* gamma = (const float*)d_in[4];
  const float* w_qkv = (const float*)d_in[5];
  const float* w_o   = (const float*)d_in[6];

  char* ws = (char*)d_ws;
  unsigned short* x_bf   = (unsigned short*)(ws);                 // 16,777,216 B
  unsigned short* wqkvT  = (unsigned short*)(ws + 16777216);      //  6,291,456 B
  unsigned short* woT    = (unsigned short*)(ws + 23068672);      //  2,097,152 B
  unsigned short* mask_rs = (unsigned short*)(ws + 25165824);     // 33,554,432 B
  unsigned char*  flags   = (unsigned char*)(ws + 25165824 + 33554432);
  unsigned short* q_r    = (unsigned short*)(ws + 75497472);      // 16,777,216 B
  unsigned short* k_r    = (unsigned short*)(ws + 92274688);      // 16,777,216 B
  unsigned short* v_t    = (unsigned short*)(ws + 109051904);     // 16,777,216 B
  unsigned short* attn   = (unsigned short*)(ws + 125829120);     // 16,777,216 B

  transpose_both_kernel<<<dim3(768 + 256), dim3(256), 0, stream>>>(w_qkv, w_o, wqkvT, woT);
  ln_kernel<<<dim3(8192), dim3(256), 0, stream>>>(x, gamma, x_bf);
  gemm_qkv_rope_kernel<<<dim3(64 * 24), dim3(256), 0, stream>>>(x_bf, wqkvT, cosb, sinb, q_r, k_r, v_t);
  mask_prep_kernel<<<dim3(4096), dim3(256), 0, stream>>>(mask, mask_rs, flags);
  attn_kernel<<<dim3(1024), dim3(256), 0, stream>>>(q_r, k_r, v_t, mask_rs, flags, attn);
  gemm_bt_kernel<1024><<<dim3(64 * 8), dim3(256), 0, stream>>>(attn, woT, (float*)d_out);
}